// Round 9
// baseline (260.337 us; speedup 1.0000x reference)
//
#include <hip/hip_runtime.h>
#include <cstdint>
#include <cstddef>

#define NN 20000
#define NE 320000

typedef short short8 __attribute__((ext_vector_type(8)));
typedef float f32x4 __attribute__((ext_vector_type(4)));
typedef unsigned short u16;

__device__ __forceinline__ float b2f(u16 u) {
  union { unsigned int i; float f; } z; z.i = ((unsigned int)u) << 16; return z.f;
}
__device__ __forceinline__ u16 f2b(float f) {
  union { float f; unsigned int i; } z; z.f = f;
  unsigned int r = z.i + 0x7fffu + ((z.i >> 16) & 1u);
  return (u16)(r >> 16);
}
// fast ELU: v_exp_f32-based, not libm expm1f
__device__ __forceinline__ float eluf(float v) {
  return v > 0.0f ? v : __expf(v) - 1.0f;
}

// ------- fused prep: features f2b (column-SLICED out) + 7 weight transposes
//         + edge histogram. virtual tid space:
//         [0,1280000): f2b 4 elems ; [1280000,1600000): hist ; rest: weights.
// (R5-proven version. The R7/R8 block-branch + LDS-tiled restructure is one
//  of two suspects for the deterministic absmax-22.18 corruption — reverted.)
__global__ __launch_bounds__(256) void k_prep(
    const float* __restrict__ features, u16* __restrict__ xbf_sliced,
    const int* __restrict__ edst, int* __restrict__ counts,
    const float* __restrict__ wr, const float* __restrict__ w1a,
    const float* __restrict__ w1b, const float* __restrict__ w2a,
    const float* __restrict__ w2b, const float* __restrict__ w3a,
    const float* __restrict__ w3b,
    u16* __restrict__ wrt, u16* __restrict__ w1at, u16* __restrict__ w1bt,
    u16* __restrict__ w2at, u16* __restrict__ w2bt, u16* __restrict__ w3at,
    u16* __restrict__ w3bt) {
  int tid = blockIdx.x * 256 + threadIdx.x;
  if (tid < 1280000) {
    int node = tid >> 6;
    int c4 = (tid & 63) * 4;           // col = c4..c4+3 (within one 64-slice)
    float4 v = *reinterpret_cast<const float4*>(features + (size_t)node * 256 + c4);
    ushort4 o;
    o.x = f2b(v.x); o.y = f2b(v.y); o.z = f2b(v.z); o.w = f2b(v.w);
    int slice = c4 >> 6, within = c4 & 63;
    *reinterpret_cast<ushort4*>(xbf_sliced + (size_t)slice * NN * 64 +
                                (size_t)node * 64 + within) = o;
    return;
  }
  if (tid < 1600000) {
    atomicAdd(&counts[edst[tid - 1280000]], 1);
    return;
  }
  int r = tid - 1600000;
  const float* Ws[7] = {wr, w1a, w1b, w2a, w2b, w3a, w3b};
  u16* Wts[7] = {wrt, w1at, w1bt, w2at, w2bt, w3at, w3bt};
  const int Kd[7] = {256, 256, 640, 640, 320, 320, 256};
  const int Nd[7] = {256, 640, 640, 320, 320, 256, 256};
  const int cnt[7] = {65536, 163840, 409600, 204800, 102400, 81920, 65536};
#pragma unroll
  for (int j = 0; j < 7; ++j) {
    if (r < cnt[j]) {
      int n = r / Kd[j], k = r - n * Kd[j];
      Wts[j][r] = f2b(Ws[j][(size_t)k * Nd[j] + n]);
      return;
    }
    r -= cnt[j];
  }
}

// x4-vectorized single-block scan; writes exclusive prefix to BOTH rs and cur.
__global__ __launch_bounds__(1024) void k_scan(const int* __restrict__ counts,
                                               int* __restrict__ rs,
                                               int* __restrict__ cur) {
  __shared__ int wsum[16];
  __shared__ int carry_s;
  int t = threadIdx.x;
  int l = t & 63, w = t >> 6;
  if (t == 0) carry_s = 0;
  __syncthreads();
  for (int base = 0; base < NN; base += 4096) {
    int idx = base + t * 4;
    int4 v = {0, 0, 0, 0};
    if (idx < NN) v = *reinterpret_cast<const int4*>(counts + idx);
    int p0 = v.x, p1 = p0 + v.y, p2 = p1 + v.z, p3 = p2 + v.w;
    int incl = p3;
#pragma unroll
    for (int off = 1; off < 64; off <<= 1) {
      int u = __shfl_up(incl, off, 64);
      if (l >= off) incl += u;
    }
    if (l == 63) wsum[w] = incl;
    __syncthreads();  // (A) wsum ready
    int carry = carry_s;
    int wpre = 0;
    for (int k2 = 0; k2 < w; ++k2) wpre += wsum[k2];
    int tot = 0;
    if (t == 0)
      for (int k2 = 0; k2 < 16; ++k2) tot += wsum[k2];
    int ex = carry + wpre + incl - p3;
    if (idx < NN) {
      int4 o;
      o.x = ex; o.y = ex + p0; o.z = ex + p1; o.w = ex + p2;
      *reinterpret_cast<int4*>(rs + idx) = o;
      *reinterpret_cast<int4*>(cur + idx) = o;
    }
    __syncthreads();  // (B) all reads of wsum/carry_s done
    if (t == 0) carry_s = carry + tot;
    __syncthreads();  // (C) carry_s updated
  }
  if (t == 0) rs[NN] = carry_s;
}

__global__ __launch_bounds__(256) void k_scatter(const int* __restrict__ src,
                                                 const int* __restrict__ dst,
                                                 int* __restrict__ cursor,
                                                 int* __restrict__ csr_src, int ne) {
  int i = blockIdx.x * 256 + threadIdx.x;
  if (i >= ne) return;
  int d = dst[i];
  int p = atomicAdd(&cursor[d], 1);
  csr_src[p] = src[i];
}

// ---- aggregation, COLUMN-SLICED gather source ------------------------------
// xs layout: [4][NN][SW] bf16 (SW = D/4). Block's slice = (blockIdx&7)&3 so —
// under round-robin blockIdx->XCD dispatch — each XCD gathers from ONE slice
// that stays resident in its 4MB L2. Classes {c, c+4} share slice c&3 and
// split the node range. Output h is NORMAL [NN][D]. ACT=1: elu(v+bias).
// This round's single change vs the passing R5 config: 16-wide edge unroll.
template <int D, int ACT>
__global__ __launch_bounds__(256) void k_agg(const u16* __restrict__ xs,
                                             const int* __restrict__ rs,
                                             const int* __restrict__ cs,
                                             const float* __restrict__ bias,
                                             u16* __restrict__ h) {
  constexpr int SW = D / 4;       // slice width (64 or 80 cols)
  constexpr int NCs = SW / 8;     // 16B chunks per slice-row (8 or 10)
  constexpr int NPB = 256 / NCs;  // nodes per block (32 or 25)
  int b = blockIdx.x;
  int cls = b & 7;
  int slice = cls & 3;
  int half = cls >> 2;
  int t = threadIdx.x;
  int nl = t / NCs, ch = t - nl * NCs;
  if (nl >= NPB) return;  // only when 256 % NCs != 0
  int node = half * 10000 + (b >> 3) * NPB + nl;
  if (node >= (half ? NN : 10000)) return;
  const u16* xp = xs + (size_t)slice * NN * SW + (size_t)ch * 8;
  float acc[8];
  {
    short8 v = *reinterpret_cast<const short8*>(xp + (size_t)node * SW);
#pragma unroll
    for (int q = 0; q < 8; ++q) acc[q] = b2f((u16)v[q]);
  }
  int e0 = rs[node], e1 = rs[node + 1];
  int e = e0;
  // 16-wide unroll: 16 independent gathers in flight (latency-bound loop)
  for (; e + 16 <= e1; e += 16) {
    int s[16];
#pragma unroll
    for (int u = 0; u < 16; ++u) s[u] = cs[e + u];
    short8 v[16];
#pragma unroll
    for (int u = 0; u < 16; ++u)
      v[u] = *reinterpret_cast<const short8*>(xp + (size_t)s[u] * SW);
#pragma unroll
    for (int q = 0; q < 8; ++q) {
      float a0 = (b2f((u16)v[0][q]) + b2f((u16)v[1][q])) +
                 (b2f((u16)v[2][q]) + b2f((u16)v[3][q]));
      float a1 = (b2f((u16)v[4][q]) + b2f((u16)v[5][q])) +
                 (b2f((u16)v[6][q]) + b2f((u16)v[7][q]));
      float a2 = (b2f((u16)v[8][q]) + b2f((u16)v[9][q])) +
                 (b2f((u16)v[10][q]) + b2f((u16)v[11][q]));
      float a3 = (b2f((u16)v[12][q]) + b2f((u16)v[13][q])) +
                 (b2f((u16)v[14][q]) + b2f((u16)v[15][q]));
      acc[q] += (a0 + a1) + (a2 + a3);
    }
  }
  for (; e + 8 <= e1; e += 8) {
    int s[8];
#pragma unroll
    for (int u = 0; u < 8; ++u) s[u] = cs[e + u];
    short8 v[8];
#pragma unroll
    for (int u = 0; u < 8; ++u)
      v[u] = *reinterpret_cast<const short8*>(xp + (size_t)s[u] * SW);
#pragma unroll
    for (int q = 0; q < 8; ++q) {
      float a0 = b2f((u16)v[0][q]) + b2f((u16)v[1][q]);
      float a1 = b2f((u16)v[2][q]) + b2f((u16)v[3][q]);
      float a2 = b2f((u16)v[4][q]) + b2f((u16)v[5][q]);
      float a3 = b2f((u16)v[6][q]) + b2f((u16)v[7][q]);
      acc[q] += (a0 + a1) + (a2 + a3);
    }
  }
  for (; e + 4 <= e1; e += 4) {
    int s0 = cs[e], s1 = cs[e + 1], s2 = cs[e + 2], s3 = cs[e + 3];
    short8 v0 = *reinterpret_cast<const short8*>(xp + (size_t)s0 * SW);
    short8 v1 = *reinterpret_cast<const short8*>(xp + (size_t)s1 * SW);
    short8 v2 = *reinterpret_cast<const short8*>(xp + (size_t)s2 * SW);
    short8 v3 = *reinterpret_cast<const short8*>(xp + (size_t)s3 * SW);
#pragma unroll
    for (int q = 0; q < 8; ++q)
      acc[q] += (b2f((u16)v0[q]) + b2f((u16)v1[q])) + (b2f((u16)v2[q]) + b2f((u16)v3[q]));
  }
  for (; e < e1; ++e) {
    int s = cs[e];
    short8 v = *reinterpret_cast<const short8*>(xp + (size_t)s * SW);
#pragma unroll
    for (int q = 0; q < 8; ++q) acc[q] += b2f((u16)v[q]);
  }
  int col0 = slice * SW + ch * 8;
  if (ACT == 1) {
    float4 b0 = *reinterpret_cast<const float4*>(bias + col0);
    float4 b1 = *reinterpret_cast<const float4*>(bias + col0 + 4);
    acc[0] = eluf(acc[0] + b0.x); acc[1] = eluf(acc[1] + b0.y);
    acc[2] = eluf(acc[2] + b0.z); acc[3] = eluf(acc[3] + b0.w);
    acc[4] = eluf(acc[4] + b1.x); acc[5] = eluf(acc[5] + b1.y);
    acc[6] = eluf(acc[6] + b1.z); acc[7] = eluf(acc[7] + b1.w);
  }
  short8 o;
#pragma unroll
  for (int q = 0; q < 8; ++q) o[q] = (short)f2b(acc[q]);
  *reinterpret_cast<short8*>(h + (size_t)node * D + col0) = o;
}

// ---------------- GEMM: C = act(A[M][K] @ B[K][N] + bias) ----------------
// A bf16 [M][K] (or column-sliced [4][M][64] when INS), Bt bf16 [N][K].
// BMx128 tile, BK=32, 3-deep prefetch ring with counted vmcnt + raw s_barrier
// (T3/T4), setprio around MFMA (T5), 4 waves (2x2), 16x16x32 bf16 MFMA,
// swizzled LDS, XCD-chunked grid. (Exact R5-proven version.)
// ACT: 0 = none (no bias), 1 = elu(v+bias), 2 = elu(elu(v+bias)).
// OSW: 0 = normal [M][N] out; else column-sliced [4][M][OSW] bf16 out.
template <int BM, int K, int N, int ACT, bool OUTF32, bool INS, int OSW>
__global__ __launch_bounds__(256) void k_gemm(const u16* __restrict__ A,
                                              const u16* __restrict__ Bt,
                                              const float* __restrict__ bias,
                                              void* __restrict__ outp, int M) {
  constexpr int NBY = (N + 127) / 128;
  constexpr int NK = K / 32;
  constexpr int ABUF = BM * 32;       // u16 per A LDS buffer
  constexpr int BUFSZ = ABUF + 4096;  // A + B per ring slot
  constexpr int MI = BM / 32;         // acc i-extent per wave
  constexpr int LPT = BM / 64 + 2;    // global_load_lds per thread per stage
  __shared__ __align__(16) u16 smem[3 * BUFSZ];
  int t = threadIdx.x;
  int l = t & 63, w = t >> 6;
  int lm = l & 15, lk = l >> 4;

  // bijective XCD-chunked swizzle (m204)
  int nb = gridDim.x;
  int q8 = nb >> 3, r8 = nb & 7;
  int orig = blockIdx.x;
  int xcd = orig & 7, idx = orig >> 3;
  int wg = (xcd < r8 ? xcd * (q8 + 1) : r8 * (q8 + 1) + (xcd - r8) * q8) + idx;
  int m0 = (wg / NBY) * BM;
  int n0 = (wg % NBY) * 128;
  int wm = (w >> 1) * (BM / 2), wn = (w & 1) * 64;

  f32x4 acc[MI][4];
#pragma unroll
  for (int i = 0; i < MI; ++i)
#pragma unroll
    for (int j = 0; j < 4; ++j)
#pragma unroll
      for (int qq = 0; qq < 4; ++qq) acc[i][j][qq] = 0.0f;

  // stage one K-slab into ring slot; k-chunk pre-swizzled in the GLOBAL
  // source (rule #21)
  auto stage = [&](int buf, int kt) {
    int k0 = kt * 32;
    u16* As = smem + buf * BUFSZ;
    u16* Bs = As + ABUF;
#pragma unroll
    for (int it = 0; it < BM / 64; ++it) {  // A
      int c = it * 256 + t;
      int row = c >> 2;
      int kc = (c & 3) ^ ((c >> 3) & 3);
      int ra = m0 + row; ra = ra < M ? ra : M - 1;
      const u16* ga;
      if (INS)  // column-sliced A: [4][M][64]; 32-col K-chunk stays in-slice
        ga = A + (size_t)(k0 >> 6) * NN * 64 + (size_t)ra * 64 + (k0 & 63) + kc * 8;
      else
        ga = A + (size_t)ra * K + k0 + kc * 8;
      __builtin_amdgcn_global_load_lds(
          (const __attribute__((address_space(1))) void*)ga,
          (__attribute__((address_space(3))) void*)(As + c * 8), 16, 0, 0);
    }
#pragma unroll
    for (int it = 0; it < 2; ++it) {        // B: 128*32 u16
      int c = it * 256 + t;
      int row = c >> 2;
      int kc = (c & 3) ^ ((c >> 3) & 3);
      int rb = n0 + row; rb = rb < N ? rb : N - 1;
      const u16* gb = Bt + (size_t)rb * K + k0 + kc * 8;
      __builtin_amdgcn_global_load_lds(
          (const __attribute__((address_space(1))) void*)gb,
          (__attribute__((address_space(3))) void*)(Bs + c * 8), 16, 0, 0);
    }
  };

  // swizzled read slot: ((row>>1)&3) == ((lm>>1)&3) for row = 16*m + lm
  int kidx = (lk ^ ((lm >> 1) & 3)) * 8;

  // 3-deep ring: stages kt+1, kt+2 stay in flight across the consume barrier.
  stage(0, 0);
  stage(1, 1);
  stage(2, 2);
  int buf = 0;
  for (int kt = 0; kt < NK; ++kt) {
    int rem = NK - 1 - kt;
    if (rem >= 2)
      asm volatile("s_waitcnt vmcnt(%0)" ::"n"(2 * LPT) : "memory");
    else if (rem == 1)
      asm volatile("s_waitcnt vmcnt(%0)" ::"n"(LPT) : "memory");
    else
      asm volatile("s_waitcnt vmcnt(0)" ::: "memory");
    __builtin_amdgcn_s_barrier();          // ring slot kt now complete everywhere
    asm volatile("" ::: "memory");         // pin ds_reads below the barrier
    const u16* As = smem + buf * BUFSZ;
    const u16* Bs = As + ABUF;
    short8 af[MI], bf[4];
#pragma unroll
    for (int i = 0; i < MI; ++i)
      af[i] = *reinterpret_cast<const short8*>(As + (wm + i * 16 + lm) * 32 + kidx);
#pragma unroll
    for (int j = 0; j < 4; ++j)
      bf[j] = *reinterpret_cast<const short8*>(Bs + (wn + j * 16 + lm) * 32 + kidx);
    __builtin_amdgcn_s_setprio(1);
#pragma unroll
    for (int i = 0; i < MI; ++i)
#pragma unroll
      for (int j = 0; j < 4; ++j)
        acc[i][j] = __builtin_amdgcn_mfma_f32_16x16x32_bf16(af[i], bf[j], acc[i][j], 0, 0, 0);
    __builtin_amdgcn_s_setprio(0);
    // drain this wave's ds_reads, then barrier: all waves done READING slot
    asm volatile("s_waitcnt lgkmcnt(0)" ::: "memory");
    __builtin_amdgcn_s_barrier();
    asm volatile("" ::: "memory");         // pin next stage below the barrier
    if (kt + 3 < NK) stage(buf, kt + 3);   // overwrite the slot just consumed
    buf = (buf == 2) ? 0 : buf + 1;
  }

  // epilogue. C/D frag layout: row = i*16 + lk*4 + qq, col = j*16 + lm.
  if (!OUTF32) {
    u16* ep = smem + w * (BM / 2) * 64;
#pragma unroll
    for (int j = 0; j < 4; ++j) {
      int col = n0 + wn + j * 16 + lm;
      float bv = (ACT > 0) ? bias[col < N ? col : N - 1] : 0.0f;
#pragma unroll
      for (int i = 0; i < MI; ++i)
#pragma unroll
        for (int qq = 0; qq < 4; ++qq) {
          float v = acc[i][j][qq];
          if (ACT > 0) { v += bv; v = eluf(v); }
          if (ACT == 2) v = eluf(v);
          ep[(i * 16 + lk * 4 + qq) * 64 + j * 16 + lm] = f2b(v);
        }
    }
    __syncthreads();
    u16* op = (u16*)outp;
#pragma unroll
    for (int u = 0; u < BM / 16; ++u) {
      int rrow = m0 + wm + u * 8 + (l >> 3);
      int col = n0 + wn + (l & 7) * 8;   // 8-col chunk, never crosses OSW bnd
      if (rrow < M && col < N) {
        short8 val = *reinterpret_cast<const short8*>(ep + u * 512 + l * 8);
        if (OSW) {
          int slice = col / OSW, within = col - slice * OSW;
          *reinterpret_cast<short8*>(op + (size_t)slice * NN * OSW +
                                     (size_t)rrow * OSW + within) = val;
        } else {
          *reinterpret_cast<short8*>(op + (size_t)rrow * N + col) = val;
        }
      }
    }
  } else {
    float* op = (float*)outp;
#pragma unroll
    for (int j = 0; j < 4; ++j) {
      int col = n0 + wn + j * 16 + lm;
      if (col >= N) continue;
      float bv = (ACT > 0) ? bias[col] : 0.0f;
#pragma unroll
      for (int i = 0; i < MI; ++i) {
        int rb = m0 + wm + i * 16 + lk * 4;
#pragma unroll
        for (int qq = 0; qq < 4; ++qq) {
          int rr = rb + qq;
          if (rr >= M) continue;
          float v = acc[i][j][qq];
          if (ACT > 0) { v += bv; v = eluf(v); }
          if (ACT == 2) v = eluf(v);
          op[(size_t)rr * N + col] = v;
        }
      }
    }
  }
}

extern "C" void kernel_launch(void* const* d_in, const int* in_sizes, int n_in,
                              void* d_out, int out_size, void* d_ws, size_t ws_size,
                              hipStream_t stream) {
  const float* features = (const float*)d_in[0];
  const int* eidx = (const int*)d_in[1];
  const float* w1a = (const float*)d_in[2];
  const float* b1a = (const float*)d_in[3];
  const float* w1b = (const float*)d_in[4];
  const float* b1b = (const float*)d_in[5];
  const float* w2a = (const float*)d_in[6];
  const float* b2a = (const float*)d_in[7];
  const float* w2b = (const float*)d_in[8];
  const float* b2b = (const float*)d_in[9];
  const float* w3a = (const float*)d_in[10];
  const float* b3a = (const float*)d_in[11];
  const float* w3b = (const float*)d_in[12];
  const float* b3b = (const float*)d_in[13];
  const float* wr = (const float*)d_in[14];
  const float* br = (const float*)d_in[15];

  char* ws = (char*)d_ws;
  u16* bufA = (u16*)(ws);                  // <= 25.6e6 B activations
  u16* bufB = (u16*)(ws + 25600000);       // same
  u16* wrt = (u16*)(ws + 51200000);        // transposed bf16 weights
  u16* w1at = wrt + 256 * 256;
  u16* w1bt = w1at + 640 * 256;
  u16* w2at = w1bt + 640 * 640;
  u16* w2bt = w2at + 320 * 640;
  u16* w3at = w2bt + 320 * 320;
  u16* w3bt = w3at + 256 * 320;
  int* row_start = (int*)(ws + 53387264);  // NN+1 ints (padded to 20004)
  int* cursor = row_start + 20004;         // NN ints
  int* csr_src = cursor + NN;              // NE ints
  int* counts = csr_src + NE;              // NN ints

  const int* esrc = eidx;
  const int* edst = eidx + NE;

  // CSR build + prep: memset -> (prep: f2b-sliced + wt + hist) -> scan -> scatter
  hipMemsetAsync(counts, 0, NN * sizeof(int), stream);
  k_prep<<<10523, 256, 0, stream>>>(features, bufA, edst, counts, wr, w1a, w1b,
                                    w2a, w2b, w3a, w3b, wrt, w1at, w1bt, w2at,
                                    w2bt, w3at, w3bt);
  k_scan<<<1, 1024, 0, stream>>>(counts, row_start, cursor);
  k_scatter<<<(NE + 255) / 256, 256, 0, stream>>>(esrc, edst, cursor, csr_src, NE);

  float* out_x = (float*)d_out;
  float* out_res = (float*)d_out + (size_t)NN * 256;

  // res = elu(X @ Wr + br)   (A = x column-sliced)
  k_gemm<64, 256, 256, 1, true, true, 0><<<dim3(313 * 2), 256, 0, stream>>>(bufA, wrt, br, out_res, NN);
  // L1: h0 = X + agg(X)   (gather sliced x -> normal h0)
  k_agg<256, 0><<<8 * 313, 256, 0, stream>>>(bufA, row_start, csr_src, nullptr, bufB);
  // t1 = elu(h0 @ w1a + b1a)
  k_gemm<64, 256, 640, 1, false, false, 0><<<dim3(313 * 5), 256, 0, stream>>>(bufB, w1at, b1a, bufA, NN);
  // x1 = elu(elu(t1 @ w1b + b1b))
  k_gemm<64, 640, 640, 2, false, false, 0><<<dim3(313 * 5), 256, 0, stream>>>(bufA, w1bt, b1b, bufB, NN);
  // L2 (agg commuted past w2a): y2 = x1 @ w2a   [320-dim, sliced out]
  k_gemm<64, 640, 320, 0, false, false, 80><<<dim3(313 * 3), 256, 0, stream>>>(bufB, w2at, nullptr, bufA, NN);
  // t2 = elu(y2 + agg(y2) + b2a)   (gather sliced y2 -> normal t2)
  k_agg<320, 1><<<8 * 400, 256, 0, stream>>>(bufA, row_start, csr_src, b2a, bufB);
  // x2 = elu(elu(t2 @ w2b + b2b))
  k_gemm<64, 320, 320, 2, false, false, 0><<<dim3(313 * 3), 256, 0, stream>>>(bufB, w2bt, b2b, bufA, NN);
  // L3 (agg commuted past w3a): y3 = x2 @ w3a   [256-dim, sliced out]
  k_gemm<64, 320, 256, 0, false, false, 64><<<dim3(313 * 2), 256, 0, stream>>>(bufA, w3at, nullptr, bufB, NN);
  // t3 = elu(y3 + agg(y3) + b3a)   (gather sliced y3 -> normal t3)
  k_agg<256, 1><<<8 * 313, 256, 0, stream>>>(bufB, row_start, csr_src, b3a, bufA);
  // x = elu(t3 @ w3b + b3b)
  k_gemm<64, 256, 256, 1, true, false, 0><<<dim3(313 * 2), 256, 0, stream>>>(bufA, w3bt, b3b, out_x, NN);
}

// Round 10
// 255.725 us; speedup vs baseline: 1.0180x; 1.0180x over previous
//
#include <hip/hip_runtime.h>
#include <cstdint>
#include <cstddef>

#define NN 20000
#define NE 320000

typedef short short8 __attribute__((ext_vector_type(8)));
typedef float f32x4 __attribute__((ext_vector_type(4)));
typedef unsigned short u16;

__device__ __forceinline__ float b2f(u16 u) {
  union { unsigned int i; float f; } z; z.i = ((unsigned int)u) << 16; return z.f;
}
__device__ __forceinline__ u16 f2b(float f) {
  union { float f; unsigned int i; } z; z.f = f;
  unsigned int r = z.i + 0x7fffu + ((z.i >> 16) & 1u);
  return (u16)(r >> 16);
}
// fast ELU: v_exp_f32-based, not libm expm1f
__device__ __forceinline__ float eluf(float v) {
  return v > 0.0f ? v : __expf(v) - 1.0f;
}

// ------- fused prep: features f2b (column-SLICED out) + 7 weight transposes
//         + edge histogram. virtual tid space:
//         [0,1280000): f2b 4 elems ; [1280000,1600000): hist ; rest: weights.
// (R5/R9-proven version. The R7/R8 block-branch + LDS-tiled restructure
//  produced deterministic absmax-22.18 corruption — permanently reverted.)
__global__ __launch_bounds__(256) void k_prep(
    const float* __restrict__ features, u16* __restrict__ xbf_sliced,
    const int* __restrict__ edst, int* __restrict__ counts,
    const float* __restrict__ wr, const float* __restrict__ w1a,
    const float* __restrict__ w1b, const float* __restrict__ w2a,
    const float* __restrict__ w2b, const float* __restrict__ w3a,
    const float* __restrict__ w3b,
    u16* __restrict__ wrt, u16* __restrict__ w1at, u16* __restrict__ w1bt,
    u16* __restrict__ w2at, u16* __restrict__ w2bt, u16* __restrict__ w3at,
    u16* __restrict__ w3bt) {
  int tid = blockIdx.x * 256 + threadIdx.x;
  if (tid < 1280000) {
    int node = tid >> 6;
    int c4 = (tid & 63) * 4;           // col = c4..c4+3 (within one 64-slice)
    float4 v = *reinterpret_cast<const float4*>(features + (size_t)node * 256 + c4);
    ushort4 o;
    o.x = f2b(v.x); o.y = f2b(v.y); o.z = f2b(v.z); o.w = f2b(v.w);
    int slice = c4 >> 6, within = c4 & 63;
    *reinterpret_cast<ushort4*>(xbf_sliced + (size_t)slice * NN * 64 +
                                (size_t)node * 64 + within) = o;
    return;
  }
  if (tid < 1600000) {
    atomicAdd(&counts[edst[tid - 1280000]], 1);
    return;
  }
  int r = tid - 1600000;
  const float* Ws[7] = {wr, w1a, w1b, w2a, w2b, w3a, w3b};
  u16* Wts[7] = {wrt, w1at, w1bt, w2at, w2bt, w3at, w3bt};
  const int Kd[7] = {256, 256, 640, 640, 320, 320, 256};
  const int Nd[7] = {256, 640, 640, 320, 320, 256, 256};
  const int cnt[7] = {65536, 163840, 409600, 204800, 102400, 81920, 65536};
#pragma unroll
  for (int j = 0; j < 7; ++j) {
    if (r < cnt[j]) {
      int n = r / Kd[j], k = r - n * Kd[j];
      Wts[j][r] = f2b(Ws[j][(size_t)k * Nd[j] + n]);
      return;
    }
    r -= cnt[j];
  }
}

// x4-vectorized single-block scan; writes exclusive prefix to BOTH rs and cur.
__global__ __launch_bounds__(1024) void k_scan(const int* __restrict__ counts,
                                               int* __restrict__ rs,
                                               int* __restrict__ cur) {
  __shared__ int wsum[16];
  __shared__ int carry_s;
  int t = threadIdx.x;
  int l = t & 63, w = t >> 6;
  if (t == 0) carry_s = 0;
  __syncthreads();
  for (int base = 0; base < NN; base += 4096) {
    int idx = base + t * 4;
    int4 v = {0, 0, 0, 0};
    if (idx < NN) v = *reinterpret_cast<const int4*>(counts + idx);
    int p0 = v.x, p1 = p0 + v.y, p2 = p1 + v.z, p3 = p2 + v.w;
    int incl = p3;
#pragma unroll
    for (int off = 1; off < 64; off <<= 1) {
      int u = __shfl_up(incl, off, 64);
      if (l >= off) incl += u;
    }
    if (l == 63) wsum[w] = incl;
    __syncthreads();  // (A) wsum ready
    int carry = carry_s;
    int wpre = 0;
    for (int k2 = 0; k2 < w; ++k2) wpre += wsum[k2];
    int tot = 0;
    if (t == 0)
      for (int k2 = 0; k2 < 16; ++k2) tot += wsum[k2];
    int ex = carry + wpre + incl - p3;
    if (idx < NN) {
      int4 o;
      o.x = ex; o.y = ex + p0; o.z = ex + p1; o.w = ex + p2;
      *reinterpret_cast<int4*>(rs + idx) = o;
      *reinterpret_cast<int4*>(cur + idx) = o;
    }
    __syncthreads();  // (B) all reads of wsum/carry_s done
    if (t == 0) carry_s = carry + tot;
    __syncthreads();  // (C) carry_s updated
  }
  if (t == 0) rs[NN] = carry_s;
}

__global__ __launch_bounds__(256) void k_scatter(const int* __restrict__ src,
                                                 const int* __restrict__ dst,
                                                 int* __restrict__ cursor,
                                                 int* __restrict__ csr_src, int ne) {
  int i = blockIdx.x * 256 + threadIdx.x;
  if (i >= ne) return;
  int d = dst[i];
  int p = atomicAdd(&cursor[d], 1);
  csr_src[p] = src[i];
}

// ---- aggregation, COLUMN-SLICED gather source ------------------------------
// xs layout: [4][NN][SW] bf16 (SW = D/4). Block's slice = (blockIdx&7)&3 so —
// under round-robin blockIdx->XCD dispatch — each XCD gathers from ONE slice
// that stays resident in its 4MB L2. Classes {c, c+4} share slice c&3 and
// split the node range. Output h is NORMAL [NN][D]. ACT=1: elu(v+bias).
template <int D, int ACT>
__global__ __launch_bounds__(256) void k_agg(const u16* __restrict__ xs,
                                             const int* __restrict__ rs,
                                             const int* __restrict__ cs,
                                             const float* __restrict__ bias,
                                             u16* __restrict__ h) {
  constexpr int SW = D / 4;       // slice width (64 or 80 cols)
  constexpr int NCs = SW / 8;     // 16B chunks per slice-row (8 or 10)
  constexpr int NPB = 256 / NCs;  // nodes per block (32 or 25)
  int b = blockIdx.x;
  int cls = b & 7;
  int slice = cls & 3;
  int half = cls >> 2;
  int t = threadIdx.x;
  int nl = t / NCs, ch = t - nl * NCs;
  if (nl >= NPB) return;  // only when 256 % NCs != 0
  int node = half * 10000 + (b >> 3) * NPB + nl;
  if (node >= (half ? NN : 10000)) return;
  const u16* xp = xs + (size_t)slice * NN * SW + (size_t)ch * 8;
  float acc[8];
  {
    short8 v = *reinterpret_cast<const short8*>(xp + (size_t)node * SW);
#pragma unroll
    for (int q = 0; q < 8; ++q) acc[q] = b2f((u16)v[q]);
  }
  int e0 = rs[node], e1 = rs[node + 1];
  int e = e0;
  // 16-wide unroll: 16 independent gathers in flight (latency-bound loop)
  for (; e + 16 <= e1; e += 16) {
    int s[16];
#pragma unroll
    for (int u = 0; u < 16; ++u) s[u] = cs[e + u];
    short8 v[16];
#pragma unroll
    for (int u = 0; u < 16; ++u)
      v[u] = *reinterpret_cast<const short8*>(xp + (size_t)s[u] * SW);
#pragma unroll
    for (int q = 0; q < 8; ++q) {
      float a0 = (b2f((u16)v[0][q]) + b2f((u16)v[1][q])) +
                 (b2f((u16)v[2][q]) + b2f((u16)v[3][q]));
      float a1 = (b2f((u16)v[4][q]) + b2f((u16)v[5][q])) +
                 (b2f((u16)v[6][q]) + b2f((u16)v[7][q]));
      float a2 = (b2f((u16)v[8][q]) + b2f((u16)v[9][q])) +
                 (b2f((u16)v[10][q]) + b2f((u16)v[11][q]));
      float a3 = (b2f((u16)v[12][q]) + b2f((u16)v[13][q])) +
                 (b2f((u16)v[14][q]) + b2f((u16)v[15][q]));
      acc[q] += (a0 + a1) + (a2 + a3);
    }
  }
  for (; e + 8 <= e1; e += 8) {
    int s[8];
#pragma unroll
    for (int u = 0; u < 8; ++u) s[u] = cs[e + u];
    short8 v[8];
#pragma unroll
    for (int u = 0; u < 8; ++u)
      v[u] = *reinterpret_cast<const short8*>(xp + (size_t)s[u] * SW);
#pragma unroll
    for (int q = 0; q < 8; ++q) {
      float a0 = b2f((u16)v[0][q]) + b2f((u16)v[1][q]);
      float a1 = b2f((u16)v[2][q]) + b2f((u16)v[3][q]);
      float a2 = b2f((u16)v[4][q]) + b2f((u16)v[5][q]);
      float a3 = b2f((u16)v[6][q]) + b2f((u16)v[7][q]);
      acc[q] += (a0 + a1) + (a2 + a3);
    }
  }
  for (; e + 4 <= e1; e += 4) {
    int s0 = cs[e], s1 = cs[e + 1], s2 = cs[e + 2], s3 = cs[e + 3];
    short8 v0 = *reinterpret_cast<const short8*>(xp + (size_t)s0 * SW);
    short8 v1 = *reinterpret_cast<const short8*>(xp + (size_t)s1 * SW);
    short8 v2 = *reinterpret_cast<const short8*>(xp + (size_t)s2 * SW);
    short8 v3 = *reinterpret_cast<const short8*>(xp + (size_t)s3 * SW);
#pragma unroll
    for (int q = 0; q < 8; ++q)
      acc[q] += (b2f((u16)v0[q]) + b2f((u16)v1[q])) + (b2f((u16)v2[q]) + b2f((u16)v3[q]));
  }
  for (; e < e1; ++e) {
    int s = cs[e];
    short8 v = *reinterpret_cast<const short8*>(xp + (size_t)s * SW);
#pragma unroll
    for (int q = 0; q < 8; ++q) acc[q] += b2f((u16)v[q]);
  }
  int col0 = slice * SW + ch * 8;
  if (ACT == 1) {
    float4 b0 = *reinterpret_cast<const float4*>(bias + col0);
    float4 b1 = *reinterpret_cast<const float4*>(bias + col0 + 4);
    acc[0] = eluf(acc[0] + b0.x); acc[1] = eluf(acc[1] + b0.y);
    acc[2] = eluf(acc[2] + b0.z); acc[3] = eluf(acc[3] + b0.w);
    acc[4] = eluf(acc[4] + b1.x); acc[5] = eluf(acc[5] + b1.y);
    acc[6] = eluf(acc[6] + b1.z); acc[7] = eluf(acc[7] + b1.w);
  }
  short8 o;
#pragma unroll
  for (int q = 0; q < 8; ++q) o[q] = (short)f2b(acc[q]);
  *reinterpret_cast<short8*>(h + (size_t)node * D + col0) = o;
}

// ---------------- GEMM: C = act(A[M][K] @ B[K][N] + bias) ----------------
// A bf16 [M][K] (or column-sliced [4][M][64] when INS), Bt bf16 [N][K].
// BMx128 tile, BK=32, 3-deep prefetch ring with counted vmcnt + raw s_barrier
// (T3/T4), issue-order fences between prologue stages, setprio around MFMA
// (T5), 4 waves (2x2), 16x16x32 bf16 MFMA, swizzled LDS, XCD-chunked grid.
// ACT: 0 = none (no bias), 1 = elu(v+bias), 2 = elu(elu(v+bias)).
// OSW: 0 = normal [M][N] out; else column-sliced [4][M][OSW] bf16 out.
template <int BM, int K, int N, int ACT, bool OUTF32, bool INS, int OSW>
__global__ __launch_bounds__(256) void k_gemm(const u16* __restrict__ A,
                                              const u16* __restrict__ Bt,
                                              const float* __restrict__ bias,
                                              void* __restrict__ outp, int M) {
  constexpr int NBY = (N + 127) / 128;
  constexpr int NK = K / 32;
  constexpr int ABUF = BM * 32;       // u16 per A LDS buffer
  constexpr int BUFSZ = ABUF + 4096;  // A + B per ring slot
  constexpr int MI = BM / 32;         // acc i-extent per wave (2 or 4)
  constexpr int LPT = BM / 64 + 2;    // global_load_lds per thread per stage
  __shared__ __align__(16) u16 smem[3 * BUFSZ];
  int t = threadIdx.x;
  int l = t & 63, w = t >> 6;
  int lm = l & 15, lk = l >> 4;

  // bijective XCD-chunked swizzle (m204)
  int nb = gridDim.x;
  int q8 = nb >> 3, r8 = nb & 7;
  int orig = blockIdx.x;
  int xcd = orig & 7, idx = orig >> 3;
  int wg = (xcd < r8 ? xcd * (q8 + 1) : r8 * (q8 + 1) + (xcd - r8) * q8) + idx;
  int m0 = (wg / NBY) * BM;
  int n0 = (wg % NBY) * 128;
  int wm = (w >> 1) * (BM / 2), wn = (w & 1) * 64;

  f32x4 acc[MI][4];
#pragma unroll
  for (int i = 0; i < MI; ++i)
#pragma unroll
    for (int j = 0; j < 4; ++j)
#pragma unroll
      for (int qq = 0; qq < 4; ++qq) acc[i][j][qq] = 0.0f;

  // stage one K-slab into ring slot; k-chunk pre-swizzled in the GLOBAL
  // source (rule #21)
  auto stage = [&](int buf, int kt) {
    int k0 = kt * 32;
    u16* As = smem + buf * BUFSZ;
    u16* Bs = As + ABUF;
#pragma unroll
    for (int it = 0; it < BM / 64; ++it) {  // A
      int c = it * 256 + t;
      int row = c >> 2;
      int kc = (c & 3) ^ ((c >> 3) & 3);
      int ra = m0 + row; ra = ra < M ? ra : M - 1;
      const u16* ga;
      if (INS)  // column-sliced A: [4][M][64]; 32-col K-chunk stays in-slice
        ga = A + (size_t)(k0 >> 6) * NN * 64 + (size_t)ra * 64 + (k0 & 63) + kc * 8;
      else
        ga = A + (size_t)ra * K + k0 + kc * 8;
      __builtin_amdgcn_global_load_lds(
          (const __attribute__((address_space(1))) void*)ga,
          (__attribute__((address_space(3))) void*)(As + c * 8), 16, 0, 0);
    }
#pragma unroll
    for (int it = 0; it < 2; ++it) {        // B: 128*32 u16
      int c = it * 256 + t;
      int row = c >> 2;
      int kc = (c & 3) ^ ((c >> 3) & 3);
      int rb = n0 + row; rb = rb < N ? rb : N - 1;
      const u16* gb = Bt + (size_t)rb * K + k0 + kc * 8;
      __builtin_amdgcn_global_load_lds(
          (const __attribute__((address_space(1))) void*)gb,
          (__attribute__((address_space(3))) void*)(Bs + c * 8), 16, 0, 0);
    }
  };

  // swizzled read slot: ((row>>1)&3) == ((lm>>1)&3) for row = 16*m + lm
  int kidx = (lk ^ ((lm >> 1) & 3)) * 8;

  // 3-deep ring: stages kt+1, kt+2 stay in flight across the consume barrier.
  // Fences keep the scheduler from mixing loads across stage boundaries
  // (counted-vmcnt semantics assume "oldest LPT = slot kt" issue order).
  stage(0, 0);
  asm volatile("" ::: "memory");
  stage(1, 1);
  asm volatile("" ::: "memory");
  stage(2, 2);
  int buf = 0;
  for (int kt = 0; kt < NK; ++kt) {
    int rem = NK - 1 - kt;
    if (rem >= 2)
      asm volatile("s_waitcnt vmcnt(%0)" ::"n"(2 * LPT) : "memory");
    else if (rem == 1)
      asm volatile("s_waitcnt vmcnt(%0)" ::"n"(LPT) : "memory");
    else
      asm volatile("s_waitcnt vmcnt(0)" ::: "memory");
    __builtin_amdgcn_s_barrier();          // ring slot kt now complete everywhere
    asm volatile("" ::: "memory");         // pin ds_reads below the barrier
    const u16* As = smem + buf * BUFSZ;
    const u16* Bs = As + ABUF;
    short8 af[MI], bf[4];
#pragma unroll
    for (int i = 0; i < MI; ++i)
      af[i] = *reinterpret_cast<const short8*>(As + (wm + i * 16 + lm) * 32 + kidx);
#pragma unroll
    for (int j = 0; j < 4; ++j)
      bf[j] = *reinterpret_cast<const short8*>(Bs + (wn + j * 16 + lm) * 32 + kidx);
    __builtin_amdgcn_s_setprio(1);
#pragma unroll
    for (int i = 0; i < MI; ++i)
#pragma unroll
      for (int j = 0; j < 4; ++j)
        acc[i][j] = __builtin_amdgcn_mfma_f32_16x16x32_bf16(af[i], bf[j], acc[i][j], 0, 0, 0);
    __builtin_amdgcn_s_setprio(0);
    // drain this wave's ds_reads, then barrier: all waves done READING slot
    asm volatile("s_waitcnt lgkmcnt(0)" ::: "memory");
    __builtin_amdgcn_s_barrier();
    asm volatile("" ::: "memory");         // pin next stage below the barrier
    if (kt + 3 < NK) stage(buf, kt + 3);   // overwrite the slot just consumed
    buf = (buf == 2) ? 0 : buf + 1;
  }

  // epilogue. C/D frag layout: row = i*16 + lk*4 + qq, col = j*16 + lm.
  if (!OUTF32) {
    u16* ep = smem + w * (BM / 2) * 64;
#pragma unroll
    for (int j = 0; j < 4; ++j) {
      int col = n0 + wn + j * 16 + lm;
      float bv = (ACT > 0) ? bias[col < N ? col : N - 1] : 0.0f;
#pragma unroll
      for (int i = 0; i < MI; ++i)
#pragma unroll
        for (int qq = 0; qq < 4; ++qq) {
          float v = acc[i][j][qq];
          if (ACT > 0) { v += bv; v = eluf(v); }
          if (ACT == 2) v = eluf(v);
          ep[(i * 16 + lk * 4 + qq) * 64 + j * 16 + lm] = f2b(v);
        }
    }
    __syncthreads();
    u16* op = (u16*)outp;
#pragma unroll
    for (int u = 0; u < BM / 16; ++u) {
      int rrow = m0 + wm + u * 8 + (l >> 3);
      int col = n0 + wn + (l & 7) * 8;   // 8-col chunk, never crosses OSW bnd
      if (rrow < M && col < N) {
        short8 val = *reinterpret_cast<const short8*>(ep + u * 512 + l * 8);
        if (OSW) {
          int slice = col / OSW, within = col - slice * OSW;
          *reinterpret_cast<short8*>(op + (size_t)slice * NN * OSW +
                                     (size_t)rrow * OSW + within) = val;
        } else {
          *reinterpret_cast<short8*>(op + (size_t)rrow * N + col) = val;
        }
      }
    }
  } else {
    float* op = (float*)outp;
#pragma unroll
    for (int j = 0; j < 4; ++j) {
      int col = n0 + wn + j * 16 + lm;
      if (col >= N) continue;
      float bv = (ACT > 0) ? bias[col] : 0.0f;
#pragma unroll
      for (int i = 0; i < MI; ++i) {
        int rb = m0 + wm + i * 16 + lk * 4;
#pragma unroll
        for (int qq = 0; qq < 4; ++qq) {
          int rr = rb + qq;
          if (rr >= M) continue;
          float v = acc[i][j][qq];
          if (ACT > 0) { v += bv; v = eluf(v); }
          if (ACT == 2) v = eluf(v);
          op[(size_t)rr * N + col] = v;
        }
      }
    }
  }
}

extern "C" void kernel_launch(void* const* d_in, const int* in_sizes, int n_in,
                              void* d_out, int out_size, void* d_ws, size_t ws_size,
                              hipStream_t stream) {
  const float* features = (const float*)d_in[0];
  const int* eidx = (const int*)d_in[1];
  const float* w1a = (const float*)d_in[2];
  const float* b1a = (const float*)d_in[3];
  const float* w1b = (const float*)d_in[4];
  const float* b1b = (const float*)d_in[5];
  const float* w2a = (const float*)d_in[6];
  const float* b2a = (const float*)d_in[7];
  const float* w2b = (const float*)d_in[8];
  const float* b2b = (const float*)d_in[9];
  const float* w3a = (const float*)d_in[10];
  const float* b3a = (const float*)d_in[11];
  const float* w3b = (const float*)d_in[12];
  const float* b3b = (const float*)d_in[13];
  const float* wr = (const float*)d_in[14];
  const float* br = (const float*)d_in[15];

  char* ws = (char*)d_ws;
  u16* bufA = (u16*)(ws);                  // <= 25.6e6 B activations
  u16* bufB = (u16*)(ws + 25600000);       // same
  u16* wrt = (u16*)(ws + 51200000);        // transposed bf16 weights
  u16* w1at = wrt + 256 * 256;
  u16* w1bt = w1at + 640 * 256;
  u16* w2at = w1bt + 640 * 640;
  u16* w2bt = w2at + 320 * 640;
  u16* w3at = w2bt + 320 * 320;
  u16* w3bt = w3at + 256 * 320;
  int* row_start = (int*)(ws + 53387264);  // NN+1 ints (padded to 20004)
  int* cursor = row_start + 20004;         // NN ints
  int* csr_src = cursor + NN;              // NE ints
  int* counts = csr_src + NE;              // NN ints

  const int* esrc = eidx;
  const int* edst = eidx + NE;

  // CSR build + prep: memset -> (prep: f2b-sliced + wt + hist) -> scan -> scatter
  hipMemsetAsync(counts, 0, NN * sizeof(int), stream);
  k_prep<<<10523, 256, 0, stream>>>(features, bufA, edst, counts, wr, w1a, w1b,
                                    w2a, w2b, w3a, w3b, wrt, w1at, w1bt, w2at,
                                    w2bt, w3at, w3bt);
  k_scan<<<1, 1024, 0, stream>>>(counts, row_start, cursor);
  k_scatter<<<(NE + 255) / 256, 256, 0, stream>>>(esrc, edst, cursor, csr_src, NE);

  float* out_x = (float*)d_out;
  float* out_res = (float*)d_out + (size_t)NN * 256;

  // res = elu(X @ Wr + br)   (A = x column-sliced)
  k_gemm<64, 256, 256, 1, true, true, 0><<<dim3(313 * 2), 256, 0, stream>>>(bufA, wrt, br, out_res, NN);
  // L1: h0 = X + agg(X)   (gather sliced x -> normal h0)
  k_agg<256, 0><<<8 * 313, 256, 0, stream>>>(bufA, row_start, csr_src, nullptr, bufB);
  // t1 = elu(h0 @ w1a + b1a)      [BM=128: 2x MFMA per staged byte]
  k_gemm<128, 256, 640, 1, false, false, 0><<<dim3(157 * 5), 256, 0, stream>>>(bufB, w1at, b1a, bufA, NN);
  // x1 = elu(elu(t1 @ w1b + b1b))
  k_gemm<128, 640, 640, 2, false, false, 0><<<dim3(157 * 5), 256, 0, stream>>>(bufA, w1bt, b1b, bufB, NN);
  // L2 (agg commuted past w2a): y2 = x1 @ w2a   [320-dim, sliced out]
  k_gemm<128, 640, 320, 0, false, false, 80><<<dim3(157 * 3), 256, 0, stream>>>(bufB, w2at, nullptr, bufA, NN);
  // t2 = elu(y2 + agg(y2) + b2a)   (gather sliced y2 -> normal t2)
  k_agg<320, 1><<<8 * 400, 256, 0, stream>>>(bufA, row_start, csr_src, b2a, bufB);
  // x2 = elu(elu(t2 @ w2b + b2b))
  k_gemm<64, 320, 320, 2, false, false, 0><<<dim3(313 * 3), 256, 0, stream>>>(bufB, w2bt, b2b, bufA, NN);
  // L3 (agg commuted past w3a): y3 = x2 @ w3a   [256-dim, sliced out]
  k_gemm<64, 320, 256, 0, false, false, 64><<<dim3(313 * 2), 256, 0, stream>>>(bufA, w3at, nullptr, bufB, NN);
  // t3 = elu(y3 + agg(y3) + b3a)   (gather sliced y3 -> normal t3)
  k_agg<256, 1><<<8 * 313, 256, 0, stream>>>(bufB, row_start, csr_src, b3a, bufA);
  // x = elu(t3 @ w3b + b3b)
  k_gemm<64, 256, 256, 1, true, false, 0><<<dim3(313 * 2), 256, 0, stream>>>(bufA, w3bt, b3b, out_x, NN);
}

// Round 11
// 245.360 us; speedup vs baseline: 1.0610x; 1.0422x over previous
//
#include <hip/hip_runtime.h>
#include <cstdint>
#include <cstddef>

#define NN 20000
#define NE 320000

typedef short short8 __attribute__((ext_vector_type(8)));
typedef float f32x4 __attribute__((ext_vector_type(4)));
typedef unsigned short u16;

__device__ __forceinline__ float b2f(u16 u) {
  union { unsigned int i; float f; } z; z.i = ((unsigned int)u) << 16; return z.f;
}
__device__ __forceinline__ u16 f2b(float f) {
  union { float f; unsigned int i; } z; z.f = f;
  unsigned int r = z.i + 0x7fffu + ((z.i >> 16) & 1u);
  return (u16)(r >> 16);
}
// fast ELU: v_exp_f32-based, not libm expm1f
__device__ __forceinline__ float eluf(float v) {
  return v > 0.0f ? v : __expf(v) - 1.0f;
}

// ------- fused prep: features f2b (column-SLICED out) + 7 weight transposes
//         + edge histogram. virtual tid space:
//         [0,1280000): f2b 4 elems ; [1280000,1600000): hist ; rest: weights.
// (R5/R9-proven version. The R7/R8 restructure caused deterministic
//  corruption — permanently reverted.)
__global__ __launch_bounds__(256) void k_prep(
    const float* __restrict__ features, u16* __restrict__ xbf_sliced,
    const int* __restrict__ edst, int* __restrict__ counts,
    const float* __restrict__ wr, const float* __restrict__ w1a,
    const float* __restrict__ w1b, const float* __restrict__ w2a,
    const float* __restrict__ w2b, const float* __restrict__ w3a,
    const float* __restrict__ w3b,
    u16* __restrict__ wrt, u16* __restrict__ w1at, u16* __restrict__ w1bt,
    u16* __restrict__ w2at, u16* __restrict__ w2bt, u16* __restrict__ w3at,
    u16* __restrict__ w3bt) {
  int tid = blockIdx.x * 256 + threadIdx.x;
  if (tid < 1280000) {
    int node = tid >> 6;
    int c4 = (tid & 63) * 4;           // col = c4..c4+3 (within one 64-slice)
    float4 v = *reinterpret_cast<const float4*>(features + (size_t)node * 256 + c4);
    ushort4 o;
    o.x = f2b(v.x); o.y = f2b(v.y); o.z = f2b(v.z); o.w = f2b(v.w);
    int slice = c4 >> 6, within = c4 & 63;
    *reinterpret_cast<ushort4*>(xbf_sliced + (size_t)slice * NN * 64 +
                                (size_t)node * 64 + within) = o;
    return;
  }
  if (tid < 1600000) {
    atomicAdd(&counts[edst[tid - 1280000]], 1);
    return;
  }
  int r = tid - 1600000;
  const float* Ws[7] = {wr, w1a, w1b, w2a, w2b, w3a, w3b};
  u16* Wts[7] = {wrt, w1at, w1bt, w2at, w2bt, w3at, w3bt};
  const int Kd[7] = {256, 256, 640, 640, 320, 320, 256};
  const int Nd[7] = {256, 640, 640, 320, 320, 256, 256};
  const int cnt[7] = {65536, 163840, 409600, 204800, 102400, 81920, 65536};
#pragma unroll
  for (int j = 0; j < 7; ++j) {
    if (r < cnt[j]) {
      int n = r / Kd[j], k = r - n * Kd[j];
      Wts[j][r] = f2b(Ws[j][(size_t)k * Nd[j] + n]);
      return;
    }
    r -= cnt[j];
  }
}

// x4-vectorized single-block scan; writes exclusive prefix to BOTH rs and cur.
__global__ __launch_bounds__(1024) void k_scan(const int* __restrict__ counts,
                                               int* __restrict__ rs,
                                               int* __restrict__ cur) {
  __shared__ int wsum[16];
  __shared__ int carry_s;
  int t = threadIdx.x;
  int l = t & 63, w = t >> 6;
  if (t == 0) carry_s = 0;
  __syncthreads();
  for (int base = 0; base < NN; base += 4096) {
    int idx = base + t * 4;
    int4 v = {0, 0, 0, 0};
    if (idx < NN) v = *reinterpret_cast<const int4*>(counts + idx);
    int p0 = v.x, p1 = p0 + v.y, p2 = p1 + v.z, p3 = p2 + v.w;
    int incl = p3;
#pragma unroll
    for (int off = 1; off < 64; off <<= 1) {
      int u = __shfl_up(incl, off, 64);
      if (l >= off) incl += u;
    }
    if (l == 63) wsum[w] = incl;
    __syncthreads();  // (A) wsum ready
    int carry = carry_s;
    int wpre = 0;
    for (int k2 = 0; k2 < w; ++k2) wpre += wsum[k2];
    int tot = 0;
    if (t == 0)
      for (int k2 = 0; k2 < 16; ++k2) tot += wsum[k2];
    int ex = carry + wpre + incl - p3;
    if (idx < NN) {
      int4 o;
      o.x = ex; o.y = ex + p0; o.z = ex + p1; o.w = ex + p2;
      *reinterpret_cast<int4*>(rs + idx) = o;
      *reinterpret_cast<int4*>(cur + idx) = o;
    }
    __syncthreads();  // (B) all reads of wsum/carry_s done
    if (t == 0) carry_s = carry + tot;
    __syncthreads();  // (C) carry_s updated
  }
  if (t == 0) rs[NN] = carry_s;
}

__global__ __launch_bounds__(256) void k_scatter(const int* __restrict__ src,
                                                 const int* __restrict__ dst,
                                                 int* __restrict__ cursor,
                                                 int* __restrict__ csr_src, int ne) {
  int i = blockIdx.x * 256 + threadIdx.x;
  if (i >= ne) return;
  int d = dst[i];
  int p = atomicAdd(&cursor[d], 1);
  csr_src[p] = src[i];
}

// ---- aggregation, COLUMN-SLICED gather source ------------------------------
// xs layout: [4][NN][SW] bf16 (SW = D/4). Block's slice = (blockIdx&7)&3 so —
// under round-robin blockIdx->XCD dispatch — each XCD gathers from ONE slice
// that stays resident in its 4MB L2. Classes {c, c+4} share slice c&3 and
// split the node range. Output h is NORMAL [NN][D]. ACT=1: elu(v+bias).
template <int D, int ACT>
__global__ __launch_bounds__(256) void k_agg(const u16* __restrict__ xs,
                                             const int* __restrict__ rs,
                                             const int* __restrict__ cs,
                                             const float* __restrict__ bias,
                                             u16* __restrict__ h) {
  constexpr int SW = D / 4;       // slice width (64 or 80 cols)
  constexpr int NCs = SW / 8;     // 16B chunks per slice-row (8 or 10)
  constexpr int NPB = 256 / NCs;  // nodes per block (32 or 25)
  int b = blockIdx.x;
  int cls = b & 7;
  int slice = cls & 3;
  int half = cls >> 2;
  int t = threadIdx.x;
  int nl = t / NCs, ch = t - nl * NCs;
  if (nl >= NPB) return;  // only when 256 % NCs != 0
  int node = half * 10000 + (b >> 3) * NPB + nl;
  if (node >= (half ? NN : 10000)) return;
  const u16* xp = xs + (size_t)slice * NN * SW + (size_t)ch * 8;
  float acc[8];
  {
    short8 v = *reinterpret_cast<const short8*>(xp + (size_t)node * SW);
#pragma unroll
    for (int q = 0; q < 8; ++q) acc[q] = b2f((u16)v[q]);
  }
  int e0 = rs[node], e1 = rs[node + 1];
  int e = e0;
  // 16-wide unroll: 16 independent gathers in flight (latency-bound loop)
  for (; e + 16 <= e1; e += 16) {
    int s[16];
#pragma unroll
    for (int u = 0; u < 16; ++u) s[u] = cs[e + u];
    short8 v[16];
#pragma unroll
    for (int u = 0; u < 16; ++u)
      v[u] = *reinterpret_cast<const short8*>(xp + (size_t)s[u] * SW);
#pragma unroll
    for (int q = 0; q < 8; ++q) {
      float a0 = (b2f((u16)v[0][q]) + b2f((u16)v[1][q])) +
                 (b2f((u16)v[2][q]) + b2f((u16)v[3][q]));
      float a1 = (b2f((u16)v[4][q]) + b2f((u16)v[5][q])) +
                 (b2f((u16)v[6][q]) + b2f((u16)v[7][q]));
      float a2 = (b2f((u16)v[8][q]) + b2f((u16)v[9][q])) +
                 (b2f((u16)v[10][q]) + b2f((u16)v[11][q]));
      float a3 = (b2f((u16)v[12][q]) + b2f((u16)v[13][q])) +
                 (b2f((u16)v[14][q]) + b2f((u16)v[15][q]));
      acc[q] += (a0 + a1) + (a2 + a3);
    }
  }
  for (; e + 8 <= e1; e += 8) {
    int s[8];
#pragma unroll
    for (int u = 0; u < 8; ++u) s[u] = cs[e + u];
    short8 v[8];
#pragma unroll
    for (int u = 0; u < 8; ++u)
      v[u] = *reinterpret_cast<const short8*>(xp + (size_t)s[u] * SW);
#pragma unroll
    for (int q = 0; q < 8; ++q) {
      float a0 = b2f((u16)v[0][q]) + b2f((u16)v[1][q]);
      float a1 = b2f((u16)v[2][q]) + b2f((u16)v[3][q]);
      float a2 = b2f((u16)v[4][q]) + b2f((u16)v[5][q]);
      float a3 = b2f((u16)v[6][q]) + b2f((u16)v[7][q]);
      acc[q] += (a0 + a1) + (a2 + a3);
    }
  }
  for (; e + 4 <= e1; e += 4) {
    int s0 = cs[e], s1 = cs[e + 1], s2 = cs[e + 2], s3 = cs[e + 3];
    short8 v0 = *reinterpret_cast<const short8*>(xp + (size_t)s0 * SW);
    short8 v1 = *reinterpret_cast<const short8*>(xp + (size_t)s1 * SW);
    short8 v2 = *reinterpret_cast<const short8*>(xp + (size_t)s2 * SW);
    short8 v3 = *reinterpret_cast<const short8*>(xp + (size_t)s3 * SW);
#pragma unroll
    for (int q = 0; q < 8; ++q)
      acc[q] += (b2f((u16)v0[q]) + b2f((u16)v1[q])) + (b2f((u16)v2[q]) + b2f((u16)v3[q]));
  }
  for (; e < e1; ++e) {
    int s = cs[e];
    short8 v = *reinterpret_cast<const short8*>(xp + (size_t)s * SW);
#pragma unroll
    for (int q = 0; q < 8; ++q) acc[q] += b2f((u16)v[q]);
  }
  int col0 = slice * SW + ch * 8;
  if (ACT == 1) {
    float4 b0 = *reinterpret_cast<const float4*>(bias + col0);
    float4 b1 = *reinterpret_cast<const float4*>(bias + col0 + 4);
    acc[0] = eluf(acc[0] + b0.x); acc[1] = eluf(acc[1] + b0.y);
    acc[2] = eluf(acc[2] + b0.z); acc[3] = eluf(acc[3] + b0.w);
    acc[4] = eluf(acc[4] + b1.x); acc[5] = eluf(acc[5] + b1.y);
    acc[6] = eluf(acc[6] + b1.z); acc[7] = eluf(acc[7] + b1.w);
  }
  short8 o;
#pragma unroll
  for (int q = 0; q < 8; ++q) o[q] = (short)f2b(acc[q]);
  *reinterpret_cast<short8*>(h + (size_t)node * D + col0) = o;
}

// ---------------- GEMM: C = act(A[M][K] @ B[K][N] + bias) ----------------
// A bf16 [M][K] (or column-sliced [4][M][64] when INS), Bt bf16 [N][K].
// BMx128 tile, BK=32, SLOTS-deep prefetch ring with counted vmcnt + raw
// s_barrier (T3/T4), issue-order fences, setprio around MFMA (T5), 4 waves,
// 16x16x32 bf16 MFMA, swizzled LDS, XCD-chunked grid.
// SLOTS=2 -> 32KB LDS (5 blocks/CU, for grids near the 3/CU capacity cliff);
// SLOTS=3 -> deeper pipeline (48KB, 3 blocks/CU at BM=128; 4 at BM=64).
// ACT: 0 = none (no bias), 1 = elu(v+bias), 2 = elu(elu(v+bias)).
// OSW: 0 = normal [M][N] out; else column-sliced [4][M][OSW] bf16 out.
template <int BM, int K, int N, int ACT, bool OUTF32, bool INS, int OSW, int SLOTS>
__global__ __launch_bounds__(256) void k_gemm(const u16* __restrict__ A,
                                              const u16* __restrict__ Bt,
                                              const float* __restrict__ bias,
                                              void* __restrict__ outp, int M) {
  constexpr int NBY = (N + 127) / 128;
  constexpr int NK = K / 32;
  constexpr int ABUF = BM * 32;       // u16 per A LDS buffer
  constexpr int BUFSZ = ABUF + 4096;  // A + B per ring slot
  constexpr int MI = BM / 32;         // acc i-extent per wave (2 or 4)
  constexpr int LPT = BM / 64 + 2;    // global_load_lds per thread per stage
  __shared__ __align__(16) u16 smem[SLOTS * BUFSZ];
  int t = threadIdx.x;
  int l = t & 63, w = t >> 6;
  int lm = l & 15, lk = l >> 4;

  // bijective XCD-chunked swizzle (m204)
  int nb = gridDim.x;
  int q8 = nb >> 3, r8 = nb & 7;
  int orig = blockIdx.x;
  int xcd = orig & 7, idx = orig >> 3;
  int wg = (xcd < r8 ? xcd * (q8 + 1) : r8 * (q8 + 1) + (xcd - r8) * q8) + idx;
  int m0 = (wg / NBY) * BM;
  int n0 = (wg % NBY) * 128;
  int wm = (w >> 1) * (BM / 2), wn = (w & 1) * 64;

  f32x4 acc[MI][4];
#pragma unroll
  for (int i = 0; i < MI; ++i)
#pragma unroll
    for (int j = 0; j < 4; ++j)
#pragma unroll
      for (int qq = 0; qq < 4; ++qq) acc[i][j][qq] = 0.0f;

  // stage one K-slab into ring slot; k-chunk pre-swizzled in the GLOBAL
  // source (rule #21)
  auto stage = [&](int buf, int kt) {
    int k0 = kt * 32;
    u16* As = smem + buf * BUFSZ;
    u16* Bs = As + ABUF;
#pragma unroll
    for (int it = 0; it < BM / 64; ++it) {  // A
      int c = it * 256 + t;
      int row = c >> 2;
      int kc = (c & 3) ^ ((c >> 3) & 3);
      int ra = m0 + row; ra = ra < M ? ra : M - 1;
      const u16* ga;
      if (INS)  // column-sliced A: [4][M][64]; 32-col K-chunk stays in-slice
        ga = A + (size_t)(k0 >> 6) * NN * 64 + (size_t)ra * 64 + (k0 & 63) + kc * 8;
      else
        ga = A + (size_t)ra * K + k0 + kc * 8;
      __builtin_amdgcn_global_load_lds(
          (const __attribute__((address_space(1))) void*)ga,
          (__attribute__((address_space(3))) void*)(As + c * 8), 16, 0, 0);
    }
#pragma unroll
    for (int it = 0; it < 2; ++it) {        // B: 128*32 u16
      int c = it * 256 + t;
      int row = c >> 2;
      int kc = (c & 3) ^ ((c >> 3) & 3);
      int rb = n0 + row; rb = rb < N ? rb : N - 1;
      const u16* gb = Bt + (size_t)rb * K + k0 + kc * 8;
      __builtin_amdgcn_global_load_lds(
          (const __attribute__((address_space(1))) void*)gb,
          (__attribute__((address_space(3))) void*)(Bs + c * 8), 16, 0, 0);
    }
  };

  // swizzled read slot: ((row>>1)&3) == ((lm>>1)&3) for row = 16*m + lm
  int kidx = (lk ^ ((lm >> 1) & 3)) * 8;

  // SLOTS-deep ring; fences keep issue order (counted-vmcnt contract).
#pragma unroll
  for (int s = 0; s < SLOTS; ++s) {
    stage(s, s);
    asm volatile("" ::: "memory");
  }
  int buf = 0;
  for (int kt = 0; kt < NK; ++kt) {
    int rem = NK - 1 - kt;
    if (SLOTS == 3) {
      if (rem >= 2)
        asm volatile("s_waitcnt vmcnt(%0)" ::"n"(2 * LPT) : "memory");
      else if (rem == 1)
        asm volatile("s_waitcnt vmcnt(%0)" ::"n"(LPT) : "memory");
      else
        asm volatile("s_waitcnt vmcnt(0)" ::: "memory");
    } else {
      if (rem >= 1)
        asm volatile("s_waitcnt vmcnt(%0)" ::"n"(LPT) : "memory");
      else
        asm volatile("s_waitcnt vmcnt(0)" ::: "memory");
    }
    __builtin_amdgcn_s_barrier();          // ring slot kt now complete everywhere
    asm volatile("" ::: "memory");         // pin ds_reads below the barrier
    const u16* As = smem + buf * BUFSZ;
    const u16* Bs = As + ABUF;
    short8 af[MI], bf[4];
#pragma unroll
    for (int i = 0; i < MI; ++i)
      af[i] = *reinterpret_cast<const short8*>(As + (wm + i * 16 + lm) * 32 + kidx);
#pragma unroll
    for (int j = 0; j < 4; ++j)
      bf[j] = *reinterpret_cast<const short8*>(Bs + (wn + j * 16 + lm) * 32 + kidx);
    __builtin_amdgcn_s_setprio(1);
#pragma unroll
    for (int i = 0; i < MI; ++i)
#pragma unroll
      for (int j = 0; j < 4; ++j)
        acc[i][j] = __builtin_amdgcn_mfma_f32_16x16x32_bf16(af[i], bf[j], acc[i][j], 0, 0, 0);
    __builtin_amdgcn_s_setprio(0);
    // drain this wave's ds_reads, then barrier: all waves done READING slot
    asm volatile("s_waitcnt lgkmcnt(0)" ::: "memory");
    __builtin_amdgcn_s_barrier();
    asm volatile("" ::: "memory");         // pin next stage below the barrier
    if (kt + SLOTS < NK) stage(buf, kt + SLOTS);  // overwrite consumed slot
    buf = (buf == SLOTS - 1) ? 0 : buf + 1;
  }

  // epilogue. C/D frag layout: row = i*16 + lk*4 + qq, col = j*16 + lm.
  if (!OUTF32) {
    u16* ep = smem + w * (BM / 2) * 64;
#pragma unroll
    for (int j = 0; j < 4; ++j) {
      int col = n0 + wn + j * 16 + lm;
      float bv = (ACT > 0) ? bias[col < N ? col : N - 1] : 0.0f;
#pragma unroll
      for (int i = 0; i < MI; ++i)
#pragma unroll
        for (int qq = 0; qq < 4; ++qq) {
          float v = acc[i][j][qq];
          if (ACT > 0) { v += bv; v = eluf(v); }
          if (ACT == 2) v = eluf(v);
          ep[(i * 16 + lk * 4 + qq) * 64 + j * 16 + lm] = f2b(v);
        }
    }
    __syncthreads();
    u16* op = (u16*)outp;
#pragma unroll
    for (int u = 0; u < BM / 16; ++u) {
      int rrow = m0 + wm + u * 8 + (l >> 3);
      int col = n0 + wn + (l & 7) * 8;   // 8-col chunk, never crosses OSW bnd
      if (rrow < M && col < N) {
        short8 val = *reinterpret_cast<const short8*>(ep + u * 512 + l * 8);
        if (OSW) {
          int slice = col / OSW, within = col - slice * OSW;
          *reinterpret_cast<short8*>(op + (size_t)slice * NN * OSW +
                                     (size_t)rrow * OSW + within) = val;
        } else {
          *reinterpret_cast<short8*>(op + (size_t)rrow * N + col) = val;
        }
      }
    }
  } else {
    float* op = (float*)outp;
#pragma unroll
    for (int j = 0; j < 4; ++j) {
      int col = n0 + wn + j * 16 + lm;
      if (col >= N) continue;
      float bv = (ACT > 0) ? bias[col] : 0.0f;
#pragma unroll
      for (int i = 0; i < MI; ++i) {
        int rb = m0 + wm + i * 16 + lk * 4;
#pragma unroll
        for (int qq = 0; qq < 4; ++qq) {
          int rr = rb + qq;
          if (rr >= M) continue;
          float v = acc[i][j][qq];
          if (ACT > 0) { v += bv; v = eluf(v); }
          if (ACT == 2) v = eluf(v);
          op[(size_t)rr * N + col] = v;
        }
      }
    }
  }
}

// ---- DUAL GEMM: two independent K=256,N=256,BM=64,ACT=1,fp32-out GEMMs in
// one launch (x = elu(t3@w3b+b3b) tiles [0,NT0), res = elu(X@wr+br) tiles
// [NT0,2*NT0); res reads column-sliced X). True overlap of the two end GEMMs.
__global__ __launch_bounds__(256) void k_gemmd(
    const u16* __restrict__ A0, const u16* __restrict__ Bt0,
    const float* __restrict__ bias0, float* __restrict__ out0,
    const u16* __restrict__ A1, const u16* __restrict__ Bt1,
    const float* __restrict__ bias1, float* __restrict__ out1) {
  constexpr int K = 256, N = 256, BM = 64;
  constexpr int NBY = 2, NK = 8, NT0 = 626;
  constexpr int ABUF = BM * 32, BUFSZ = ABUF + 4096, MI = 2, LPT = 3;
  constexpr int SLOTS = 3;
  __shared__ __align__(16) u16 smem[SLOTS * BUFSZ];
  int t = threadIdx.x;
  int l = t & 63, w = t >> 6;
  int lm = l & 15, lk = l >> 4;

  int nb = gridDim.x;
  int q8 = nb >> 3, r8 = nb & 7;
  int orig = blockIdx.x;
  int xcd = orig & 7, idx = orig >> 3;
  int wg = (xcd < r8 ? xcd * (q8 + 1) : r8 * (q8 + 1) + (xcd - r8) * q8) + idx;
  bool second = wg >= NT0;
  int tt = second ? wg - NT0 : wg;
  const u16* A = second ? A1 : A0;
  const u16* Bt = second ? Bt1 : Bt0;
  const float* bias = second ? bias1 : bias0;
  float* op = second ? out1 : out0;

  int m0 = (tt / NBY) * BM;
  int n0 = (tt % NBY) * 128;
  int wm = (w >> 1) * (BM / 2), wn = (w & 1) * 64;

  f32x4 acc[MI][4];
#pragma unroll
  for (int i = 0; i < MI; ++i)
#pragma unroll
    for (int j = 0; j < 4; ++j)
#pragma unroll
      for (int qq = 0; qq < 4; ++qq) acc[i][j][qq] = 0.0f;

  auto stage = [&](int buf, int kt) {
    int k0 = kt * 32;
    u16* As = smem + buf * BUFSZ;
    u16* Bs = As + ABUF;
    {
      int c = t;
      int row = c >> 2;
      int kc = (c & 3) ^ ((c >> 3) & 3);
      int ra = m0 + row; ra = ra < NN ? ra : NN - 1;
      const u16* ga;
      if (second)  // column-sliced X: [4][NN][64]
        ga = A + (size_t)(k0 >> 6) * NN * 64 + (size_t)ra * 64 + (k0 & 63) + kc * 8;
      else
        ga = A + (size_t)ra * K + k0 + kc * 8;
      __builtin_amdgcn_global_load_lds(
          (const __attribute__((address_space(1))) void*)ga,
          (__attribute__((address_space(3))) void*)(As + c * 8), 16, 0, 0);
    }
#pragma unroll
    for (int it = 0; it < 2; ++it) {
      int c = it * 256 + t;
      int row = c >> 2;
      int kc = (c & 3) ^ ((c >> 3) & 3);
      int rb = n0 + row; rb = rb < N ? rb : N - 1;
      const u16* gb = Bt + (size_t)rb * K + k0 + kc * 8;
      __builtin_amdgcn_global_load_lds(
          (const __attribute__((address_space(1))) void*)gb,
          (__attribute__((address_space(3))) void*)(Bs + c * 8), 16, 0, 0);
    }
  };

  int kidx = (lk ^ ((lm >> 1) & 3)) * 8;

#pragma unroll
  for (int s = 0; s < SLOTS; ++s) {
    stage(s, s);
    asm volatile("" ::: "memory");
  }
  int buf = 0;
  for (int kt = 0; kt < NK; ++kt) {
    int rem = NK - 1 - kt;
    if (rem >= 2)
      asm volatile("s_waitcnt vmcnt(%0)" ::"n"(2 * LPT) : "memory");
    else if (rem == 1)
      asm volatile("s_waitcnt vmcnt(%0)" ::"n"(LPT) : "memory");
    else
      asm volatile("s_waitcnt vmcnt(0)" ::: "memory");
    __builtin_amdgcn_s_barrier();
    asm volatile("" ::: "memory");
    const u16* As = smem + buf * BUFSZ;
    const u16* Bs = As + ABUF;
    short8 af[MI], bf[4];
#pragma unroll
    for (int i = 0; i < MI; ++i)
      af[i] = *reinterpret_cast<const short8*>(As + (wm + i * 16 + lm) * 32 + kidx);
#pragma unroll
    for (int j = 0; j < 4; ++j)
      bf[j] = *reinterpret_cast<const short8*>(Bs + (wn + j * 16 + lm) * 32 + kidx);
    __builtin_amdgcn_s_setprio(1);
#pragma unroll
    for (int i = 0; i < MI; ++i)
#pragma unroll
      for (int j = 0; j < 4; ++j)
        acc[i][j] = __builtin_amdgcn_mfma_f32_16x16x32_bf16(af[i], bf[j], acc[i][j], 0, 0, 0);
    __builtin_amdgcn_s_setprio(0);
    asm volatile("s_waitcnt lgkmcnt(0)" ::: "memory");
    __builtin_amdgcn_s_barrier();
    asm volatile("" ::: "memory");
    if (kt + SLOTS < NK) stage(buf, kt + SLOTS);
    buf = (buf == SLOTS - 1) ? 0 : buf + 1;
  }

#pragma unroll
  for (int j = 0; j < 4; ++j) {
    int col = n0 + wn + j * 16 + lm;
    float bv = bias[col];
#pragma unroll
    for (int i = 0; i < MI; ++i) {
      int rb = m0 + wm + i * 16 + lk * 4;
#pragma unroll
      for (int qq = 0; qq < 4; ++qq) {
        int rr = rb + qq;
        if (rr >= NN) continue;
        float v = eluf(acc[i][j][qq] + bv);
        op[(size_t)rr * N + col] = v;
      }
    }
  }
}

extern "C" void kernel_launch(void* const* d_in, const int* in_sizes, int n_in,
                              void* d_out, int out_size, void* d_ws, size_t ws_size,
                              hipStream_t stream) {
  const float* features = (const float*)d_in[0];
  const int* eidx = (const int*)d_in[1];
  const float* w1a = (const float*)d_in[2];
  const float* b1a = (const float*)d_in[3];
  const float* w1b = (const float*)d_in[4];
  const float* b1b = (const float*)d_in[5];
  const float* w2a = (const float*)d_in[6];
  const float* b2a = (const float*)d_in[7];
  const float* w2b = (const float*)d_in[8];
  const float* b2b = (const float*)d_in[9];
  const float* w3a = (const float*)d_in[10];
  const float* b3a = (const float*)d_in[11];
  const float* w3b = (const float*)d_in[12];
  const float* b3b = (const float*)d_in[13];
  const float* wr = (const float*)d_in[14];
  const float* br = (const float*)d_in[15];

  char* ws = (char*)d_ws;
  u16* bufX = (u16*)(ws);                  // sliced x: 4*NN*64*2 = 10.24 MB
  u16* bufA = (u16*)(ws + 10240000);       // activations <= 25.6 MB
  u16* bufB = (u16*)(ws + 35840000);       // activations <= 25.6 MB
  u16* wrt = (u16*)(ws + 61440000);        // transposed bf16 weights
  u16* w1at = wrt + 256 * 256;
  u16* w1bt = w1at + 640 * 256;
  u16* w2at = w1bt + 640 * 640;
  u16* w2bt = w2at + 320 * 640;
  u16* w3at = w2bt + 320 * 320;
  u16* w3bt = w3at + 256 * 320;
  int* row_start = (int*)(ws + 63700992);  // NN+1 ints (padded to 20004)
  int* cursor = row_start + 20004;         // NN ints
  int* csr_src = cursor + NN;              // NE ints
  int* counts = csr_src + NE;              // NN ints

  const int* esrc = eidx;
  const int* edst = eidx + NE;

  // CSR build + prep: memset -> (prep: f2b-sliced + wt + hist) -> scan -> scatter
  hipMemsetAsync(counts, 0, NN * sizeof(int), stream);
  k_prep<<<10523, 256, 0, stream>>>(features, bufX, edst, counts, wr, w1a, w1b,
                                    w2a, w2b, w3a, w3b, wrt, w1at, w1bt, w2at,
                                    w2bt, w3at, w3bt);
  k_scan<<<1, 1024, 0, stream>>>(counts, row_start, cursor);
  k_scatter<<<(NE + 255) / 256, 256, 0, stream>>>(esrc, edst, cursor, csr_src, NE);

  float* out_x = (float*)d_out;
  float* out_res = (float*)d_out + (size_t)NN * 256;

  // L1: h0 = X + agg(X)   (gather sliced x -> normal h0)
  k_agg<256, 0><<<8 * 313, 256, 0, stream>>>(bufX, row_start, csr_src, nullptr, bufA);
  // t1 = elu(h0 @ w1a + b1a)   [SLOTS=2: 32KB LDS -> 5 blk/CU, single round]
  k_gemm<128, 256, 640, 1, false, false, 0, 2><<<dim3(157 * 5), 256, 0, stream>>>(bufA, w1at, b1a, bufB, NN);
  // x1 = elu(elu(t1 @ w1b + b1b))
  k_gemm<128, 640, 640, 2, false, false, 0, 2><<<dim3(157 * 5), 256, 0, stream>>>(bufB, w1bt, b1b, bufA, NN);
  // L2 (agg commuted past w2a): y2 = x1 @ w2a   [320-dim, sliced out]
  k_gemm<128, 640, 320, 0, false, false, 80, 3><<<dim3(157 * 3), 256, 0, stream>>>(bufA, w2at, nullptr, bufB, NN);
  // t2 = elu(y2 + agg(y2) + b2a)   (gather sliced y2 -> normal t2)
  k_agg<320, 1><<<8 * 400, 256, 0, stream>>>(bufB, row_start, csr_src, b2a, bufA);
  // x2 = elu(elu(t2 @ w2b + b2b))
  k_gemm<64, 320, 320, 2, false, false, 0, 3><<<dim3(313 * 3), 256, 0, stream>>>(bufA, w2bt, b2b, bufB, NN);
  // L3 (agg commuted past w3a): y3 = x2 @ w3a   [256-dim, sliced out]
  k_gemm<64, 320, 256, 0, false, false, 64, 3><<<dim3(313 * 2), 256, 0, stream>>>(bufB, w3at, nullptr, bufA, NN);
  // t3 = elu(y3 + agg(y3) + b3a)   (gather sliced y3 -> normal t3)
  k_agg<256, 1><<<8 * 313, 256, 0, stream>>>(bufA, row_start, csr_src, b3a, bufB);
  // x = elu(t3 @ w3b + b3b)  AND  res = elu(X @ wr + br)  (fused dual launch)
  k_gemmd<<<dim3(626 * 2), 256, 0, stream>>>(bufB, w3bt, b3b, out_x,
                                             bufX, wrt, br, out_res);
}